// Round 9
// baseline (200.072 us; speedup 1.0000x reference)
//
#include <hip/hip_runtime.h>
#include <math.h>

#define BATCH 32
#define HIN   224
#define WIN   224
#define CIN   3
#define KOUT  64
#define RK    5
#define HOUT  220
#define WOUT  220

#define TH     16                 // mu tile: 16 output rows
#define TW     32                 // x 32 output px
#define PATCH_H (TH + RK - 1)     // 20
#define PATCH_W (TW + RK - 1)     // 36
#define SROW_F  112               // padded staged-row floats (108 valid)
#define NTOT ((size_t)BATCH * HOUT * WOUT * KOUT)

typedef float  v4f    __attribute__((ext_vector_type(4)));
typedef short  short8 __attribute__((ext_vector_type(8)));   // 8 bf16 = 4 VGPRs

// d_ws layout: [0,12288): 768 x short8 weight frags  [12288,12544): 64 f32 softplus(w_sigma)
#define WS_WF_FRAGS 768
#define WS_WSG_OFF  12288

// --- HW transcendentals: v_exp_f32 = 2^x, v_log_f32 = log2(x) ---
__device__ __forceinline__ float exp2_hw(float x) { float r; asm("v_exp_f32 %0, %1" : "=v"(r) : "v"(x)); return r; }
__device__ __forceinline__ float log2_hw(float x) { float r; asm("v_log_f32 %0, %1" : "=v"(r) : "v"(x)); return r; }
#define LOG2E 1.44269504088896f
#define LN2   0.69314718055995f

__device__ __forceinline__ float softplus_hw(float x) {       // general, stable
    float t = exp2_hw(-fabsf(x) * LOG2E);
    return fmaxf(x, 0.0f) + LN2 * log2_hw(1.0f + t);
}
__device__ __forceinline__ float softplus_pos(float y) {      // y >= 0 fast path
    return y + LN2 * log2_hw(1.0f + exp2_hw(-y * LOG2E));
}
__device__ __forceinline__ short f2bf(float x) {              // f32 -> bf16 bits, RNE
    unsigned u = __float_as_uint(x);
    u = (u + 0x7FFFu + ((u >> 16) & 1u)) >> 16;
    return (short)u;
}

// ---- prep: pack weight MFMA fragments (bf16) + softplus(w_sigma) + KL ----
// A-frag (16x16x32, M=16 ch): row = lane&15, k = (lane>>4)*8 + i.
// k-order: k = kh*16 + (kw*3 + c); inner==15 and k>=80 are zero pads.
__global__ __launch_bounds__(256) void vdp_prep_kernel(
    const float* __restrict__ w_mu, const float* __restrict__ w_sigma,
    void* __restrict__ ws, float* __restrict__ out)
{
    __shared__ float red[4];
    short8* wf = (short8*)ws;
    float* wsg = (float*)((char*)ws + WS_WSG_OFF);
    const int t = threadIdx.x;

    for (int f = t; f < WS_WF_FRAGS; f += 256) {   // f = (s*4+nb)*64 + lane
        const int s  = f >> 8;
        const int nb = (f >> 6) & 3;
        const int l  = f & 63;
        const int ch = nb * 16 + (l & 15);
        const int h2 = l >> 4;
        short8 r;
        #pragma unroll
        for (int i = 0; i < 8; ++i) {
            const int k = s * 32 + h2 * 8 + i;
            const int kh = k >> 4, inner = k & 15;
            float v = 0.0f;
            if (inner < 15 && k < 80) {
                const int kw = inner / 3;
                const int c  = inner - kw * 3;
                v = w_mu[((kh * 5 + kw) * 3 + c) * KOUT + ch];
            }
            r[i] = f2bf(v);
        }
        wf[f] = r;
    }
    if (t < KOUT) wsg[t] = softplus_hw(w_sigma[t]);

    // ---- KL scalar ----
    float s = 0.0f;
    for (int i = t; i < RK * RK * CIN * KOUT; i += 256) {
        const float v = w_mu[i];
        s = fmaf(v, v, s);
    }
    float u = s * (100.0f / 4800.0f);
    if (t < KOUT) {
        const float wsv = w_sigma[t];
        u += (-wsv + softplus_hw(wsv) * 100.0f) * (1.0f / 64.0f);
    }
    #pragma unroll
    for (int off = 32; off > 0; off >>= 1)
        u += __shfl_down(u, off, 64);
    if ((t & 63) == 0) red[t >> 6] = u;
    __syncthreads();
    if (t == 0) {
        const float U = red[0] + red[1] + red[2] + red[3];
        out[2 * NTOT] = 0.5f * (-4.6051701860f - 1.0f + U);
    }
}

// ---- mu kernel: single write stream; block = 16 rows x 32 px; wave = 4 rows ----
__global__ __launch_bounds__(256, 4) void vdp_mu_kernel(
    const float* __restrict__ mu_in, const void* __restrict__ ws, float* __restrict__ out)
{
    __shared__ float s_row[PATCH_H][SROW_F];     // 20 x 112 f32 (8.75 KB)

    const int tid  = threadIdx.x;
    const int lane = tid & 63;
    const int wid  = tid >> 6;
    const int p    = lane & 15;            // pixel col within group
    const int h2   = lane >> 4;            // k subgroup

    const int b = blockIdx.z;
    int ho0 = blockIdx.y * TH; if (ho0 > HOUT - TH) ho0 = HOUT - TH;  // 204 (overlap recompute)
    int wo0 = blockIdx.x * TW; if (wo0 > WOUT - TW) wo0 = WOUT - TW;  // 188

    // weight frags (L2/L3-hot, coalesced)
    const short8* wfg = (const short8*)ws;
    short8 wf[12];
    #pragma unroll
    for (int f = 0; f < 12; ++f) wf[f] = wfg[f * 64 + lane];

    // stage 20 input rows x 108 floats (cols 108..111 zeroed)
    const size_t inbase = ((size_t)b * HIN + ho0) * (WIN * CIN) + wo0 * CIN;
    for (int idx = tid; idx < PATCH_H * SROW_F; idx += 256) {
        const int r = idx / SROW_F, c = idx - r * SROW_F;
        float v = 0.0f;
        if (c < PATCH_W * CIN) v = mu_in[inbase + (size_t)r * (WIN * CIN) + c];
        s_row[r][c] = v;
    }
    __syncthreads();

    #pragma unroll 1
    for (int j = 0; j < 4; ++j) {
        const int rt = (wid << 2) | j;
        const size_t rowbase = (((size_t)b * HOUT + ho0 + rt) * WOUT + wo0) * KOUT;

        #pragma unroll
        for (int g = 0; g < 2; ++g) {
            short8 pf[3];
            #pragma unroll
            for (int s = 0; s < 3; ++s) {
                int ridx = rt + 2 * s + (h2 >> 1);
                ridx = ridx > PATCH_H - 1 ? PATCH_H - 1 : ridx;   // k>=80 pad: value x 0-weight
                const float* rp = &s_row[ridx][3 * (16 * g + p) + 8 * (h2 & 1)];
                short8 r;
                #pragma unroll
                for (int i = 0; i < 8; ++i) r[i] = f2bf(rp[i]);
                pf[s] = r;
            }
            v4f acc[4];
            #pragma unroll
            for (int nb = 0; nb < 4; ++nb) {
                v4f a = {0.0f, 0.0f, 0.0f, 0.0f};
                #pragma unroll
                for (int s = 0; s < 3; ++s)
                    a = __builtin_amdgcn_mfma_f32_16x16x32_bf16(wf[s * 4 + nb], pf[s], a, 0, 0, 0);
                acc[nb] = a;
            }
            // D col = pixel, rows = 4 ch at nb*16 + h2*4 (sector-complete stores)
            float* mp = out + rowbase + (size_t)(16 * g + p) * KOUT + h2 * 4;
            #pragma unroll
            for (int nb = 0; nb < 4; ++nb)
                *(v4f*)(mp + nb * 16) = acc[nb];
        }
    }
}

// ---- sigma kernel: single write stream; block = 4 rows x 220 px (full width) ----
// separable 5x5 box: ssq -> column-sums (5 rows) -> row window (5 cols)
__global__ __launch_bounds__(256, 4) void vdp_sigma_kernel(
    const float* __restrict__ mu_in, const void* __restrict__ ws, float* __restrict__ out)
{
    __shared__ float s_row[8 * 672];      // 8 full input rows (21 KB)
    __shared__ float s_ssq[8][224];       // per-pixel sum_c x^2 (7 KB)
    __shared__ float s_cs[4][224];        // 5-row column sums (3.5 KB)

    const int tid  = threadIdx.x;
    const int lane = tid & 63;
    const int wid  = tid >> 6;            // = output row in band
    const int p    = lane & 15;           // ch-group: ch = 4p..4p+3
    const int h2   = lane >> 4;           // px-in-quad

    const int b  = blockIdx.y;
    const int r0 = blockIdx.x * 4;        // 0..216 exact

    const float* wsg_g = (const float*)((const char*)ws + WS_WSG_OFF);
    const v4f wsg_kg = *(const v4f*)(wsg_g + p * 4);

    // stage 8 contiguous full rows (21.5 KB, pure dwordx4 coalesced)
    {
        const v4f* gin = (const v4f*)(mu_in + ((size_t)b * HIN + r0) * (WIN * CIN));
        v4f* dst = (v4f*)s_row;
        for (int i = tid; i < 8 * 672 / 4; i += 256) dst[i] = gin[i];
    }
    __syncthreads();

    // per-pixel channel-summed squares (8 x 224)
    for (int idx = tid; idx < 8 * 224; idx += 256) {
        const int r = idx >> 5 >> 3;                  // idx/256? no: compute directly
        const int rr = idx / 224, px = idx - rr * 224;
        const float* q = &s_row[rr * 672 + 3 * px];
        s_ssq[rr][px] = fmaf(q[0], q[0], fmaf(q[1], q[1], q[2] * q[2]));
        (void)r;
    }
    __syncthreads();

    // column sums over 5 rows (4 x 224)
    for (int idx = tid; idx < 4 * 224; idx += 256) {
        const int rr = idx / 224, px = idx - rr * 224;
        s_cs[rr][px] = s_ssq[rr][px] + s_ssq[rr + 1][px] + s_ssq[rr + 2][px]
                     + s_ssq[rr + 3][px] + s_ssq[rr + 4][px];
    }
    __syncthreads();

    // store: wave = 1 output row, 55 x 1KB contiguous wave-stores (56 KB/row)
    const int rt = wid;
    float* sp = out + NTOT + (((size_t)b * HOUT + r0 + rt) * WOUT) * KOUT + p * 4;
    #pragma unroll 1
    for (int q = 0; q < 55; ++q) {
        const int px = (q << 2) | h2;
        const float sq = (s_cs[rt][px] + s_cs[rt][px + 1] + s_cs[rt][px + 2]
                        + s_cs[rt][px + 3] + s_cs[rt][px + 4]) * (1.0f / 75.0f);
        v4f sg;
        sg.x = softplus_pos(wsg_kg.x * sq);
        sg.y = softplus_pos(wsg_kg.y * sq);
        sg.z = softplus_pos(wsg_kg.z * sq);
        sg.w = softplus_pos(wsg_kg.w * sq);
        *(v4f*)(sp + (size_t)px * KOUT) = sg;
    }
}

extern "C" void kernel_launch(void* const* d_in, const int* in_sizes, int n_in,
                              void* d_out, int out_size, void* d_ws, size_t ws_size,
                              hipStream_t stream)
{
    (void)in_sizes; (void)n_in; (void)ws_size; (void)out_size;
    const float* mu_in   = (const float*)d_in[0];
    const float* w_mu    = (const float*)d_in[1];
    const float* w_sigma = (const float*)d_in[2];
    float* out = (float*)d_out;

    vdp_prep_kernel<<<1, 256, 0, stream>>>(w_mu, w_sigma, d_ws, out);
    dim3 grid_mu((WOUT + TW - 1) / TW, (HOUT + TH - 1) / TH, BATCH);  // 7 x 14 x 32 = 3136
    vdp_mu_kernel<<<grid_mu, 256, 0, stream>>>(mu_in, d_ws, out);
    dim3 grid_sg(HOUT / 4, BATCH, 1);                                 // 55 x 32 = 1760
    vdp_sigma_kernel<<<grid_sg, 256, 0, stream>>>(mu_in, d_ws, out);
}

// Round 10
// 185.802 us; speedup vs baseline: 1.0768x; 1.0768x over previous
//
#include <hip/hip_runtime.h>
#include <math.h>

#define BATCH 32
#define HIN   224
#define WIN   224
#define CIN   3
#define KOUT  64
#define RK    5
#define HOUT  220
#define WOUT  220

#define TS       16                 // tile: 16x16 output px
#define PATCH    20
#define NT_TILES (14 * 14 * BATCH)  // 6272
#define NBLK     1024
#define NTOT ((size_t)BATCH * HOUT * WOUT * KOUT)

typedef float  v4f    __attribute__((ext_vector_type(4)));
typedef short  short8 __attribute__((ext_vector_type(8)));   // 8 bf16 = 4 VGPRs

// d_ws: [0,12288) 768 x short8 weight frags | [12288,12544) 64 f32 softplus(w_sigma)
//       [12544,12548) tile counter
#define WS_WF_FRAGS 768
#define WS_WSG_OFF  12288
#define WS_CNT_OFF  12544

__device__ __forceinline__ float exp2_hw(float x) { float r; asm("v_exp_f32 %0, %1" : "=v"(r) : "v"(x)); return r; }
__device__ __forceinline__ float log2_hw(float x) { float r; asm("v_log_f32 %0, %1" : "=v"(r) : "v"(x)); return r; }
#define LOG2E 1.44269504088896f
#define LN2   0.69314718055995f

__device__ __forceinline__ float softplus_hw(float x) {       // general, stable
    float t = exp2_hw(-fabsf(x) * LOG2E);
    return fmaxf(x, 0.0f) + LN2 * log2_hw(1.0f + t);
}
__device__ __forceinline__ float softplus_pos(float y) {      // y >= 0 fast path
    return y + LN2 * log2_hw(1.0f + exp2_hw(-y * LOG2E));
}
__device__ __forceinline__ short f2bf(float x) {              // f32 -> bf16, RNE (prep only)
    unsigned u = __float_as_uint(x);
    u = (u + 0x7FFFu + ((u >> 16) & 1u)) >> 16;
    return (short)u;
}

// ---- prep: weight frags (bf16) + softplus(w_sigma) + KL + counter reset ----
// A-frag (16x16x32, M=16 ch): row = lane&15, k = (lane>>4)*8 + i.
// k-order: k = kh*16 + (kw*3 + c); inner==15 and k>=80 are zero pads.
__global__ __launch_bounds__(256) void vdp_prep_kernel(
    const float* __restrict__ w_mu, const float* __restrict__ w_sigma,
    void* __restrict__ ws, float* __restrict__ out)
{
    __shared__ float red[4];
    short8* wf = (short8*)ws;
    float* wsg = (float*)((char*)ws + WS_WSG_OFF);
    const int t = threadIdx.x;

    if (t == 0) *(int*)((char*)ws + WS_CNT_OFF) = NBLK;   // reset work-steal counter

    for (int f = t; f < WS_WF_FRAGS; f += 256) {   // f = (s*4+nb)*64 + lane
        const int s  = f >> 8;
        const int nb = (f >> 6) & 3;
        const int l  = f & 63;
        const int ch = nb * 16 + (l & 15);
        const int h2 = l >> 4;
        short8 r;
        #pragma unroll
        for (int i = 0; i < 8; ++i) {
            const int k = s * 32 + h2 * 8 + i;
            const int kh = k >> 4, inner = k & 15;
            float v = 0.0f;
            if (inner < 15 && k < 80) {
                const int kw = inner / 3;
                const int c  = inner - kw * 3;
                v = w_mu[((kh * 5 + kw) * 3 + c) * KOUT + ch];
            }
            r[i] = f2bf(v);
        }
        wf[f] = r;
    }
    if (t < KOUT) wsg[t] = softplus_hw(w_sigma[t]);

    float s = 0.0f;
    for (int i = t; i < RK * RK * CIN * KOUT; i += 256) {
        const float v = w_mu[i];
        s = fmaf(v, v, s);
    }
    float u = s * (100.0f / 4800.0f);
    if (t < KOUT) {
        const float wsv = w_sigma[t];
        u += (-wsv + softplus_hw(wsv) * 100.0f) * (1.0f / 64.0f);
    }
    #pragma unroll
    for (int off = 32; off > 0; off >>= 1)
        u += __shfl_down(u, off, 64);
    if ((t & 63) == 0) red[t >> 6] = u;
    __syncthreads();
    if (t == 0) {
        const float U = red[0] + red[1] + red[2] + red[3];
        out[2 * NTOT] = 0.5f * (-4.6051701860f - 1.0f + U);
    }
}

// async stage of one tile's 20x64-float patch into LDS buf (linear dest, 16B chunks)
__device__ __forceinline__ void stage_tile(const float* __restrict__ mu_in, int t,
                                           float* buf, int tid)
{
    const int b  = t / 196;
    const int r2 = t - b * 196;
    int ho0 = (r2 / 14) * TS; if (ho0 > HOUT - TS) ho0 = HOUT - TS;
    int wo0 = (r2 % 14) * TS; if (wo0 > WOUT - TS) wo0 = WOUT - TS;
    const float* gb = mu_in + ((size_t)b * HIN + ho0) * (WIN * CIN) + wo0 * CIN;
    #pragma unroll
    for (int it = 0; it < 2; ++it) {
        const int ci = it * 256 + (tid & ~63);       // wave-uniform chunk base
        if (ci < 320) {                              // 320 = 20 rows x 16 chunks
            const int il = ci + (tid & 63);
            const int r  = il >> 4;
            int cc = il & 15; if (cc > 14) cc = 14;  // clamp pad chunk (dup data, zero-weight slots)
            const float* g = gb + r * (WIN * CIN) + cc * 4;
            __builtin_amdgcn_global_load_lds(
                (const __attribute__((address_space(1))) void*)g,
                (__attribute__((address_space(3))) void*)(buf + ci * 4),
                16, 0, 0);
        }
    }
}

// ---- persistent conv: 1024 blocks, work-stealing, double-buffered staging ----
__global__ __launch_bounds__(256, 4) void vdp_conv_kernel(
    const float* __restrict__ mu_in, void* __restrict__ ws, float* __restrict__ out)
{
    __shared__ float s_row[2][PATCH * 64];   // double-buffered patch (10 KB)
    __shared__ float s_ssq[PATCH][PATCH];    // per-pixel sum_c x^2
    __shared__ float s_sq[TS * TS];          // 5x5 box mean
    __shared__ int   s_next;

    const int tid  = threadIdx.x;
    const int lane = tid & 63;
    const int wid  = tid >> 6;
    const int p    = lane & 15;              // MFMA: pixel col; sigma: ch-group kg
    const int h2   = lane >> 4;              // MFMA: k subgroup;  sigma: px quad

    int* cnt = (int*)((char*)ws + WS_CNT_OFF);

    // weight frags: once per persistent block
    const short8* wfg = (const short8*)ws;
    short8 wf[12];
    #pragma unroll
    for (int f = 0; f < 12; ++f) wf[f] = wfg[f * 64 + lane];
    const float* wsg_g = (const float*)((const char*)ws + WS_WSG_OFF);
    const v4f wsg_kg = *(const v4f*)(wsg_g + p * 4);

    int t = blockIdx.x;
    int cur = 0;
    stage_tile(mu_in, t, s_row[0], tid);

    while (t < NT_TILES) {
        __syncthreads();                     // stage(t) drained (vmcnt0 at barrier)

        const float* srow = s_row[cur];

        if (tid == 0) s_next = atomicAdd(cnt, 1);

        // per-pixel channel-summed squares (20 x 20)
        for (int idx = tid; idx < PATCH * PATCH; idx += 256) {
            const int r = idx / PATCH;
            const int px = idx - r * PATCH;
            const float x0 = srow[r * 64 + 3 * px], x1 = srow[r * 64 + 3 * px + 1],
                        x2 = srow[r * 64 + 3 * px + 2];
            s_ssq[r][px] = fmaf(x0, x0, fmaf(x1, x1, x2 * x2));
        }
        __syncthreads();

        // 5x5 box mean (one thread per tile pixel)
        {
            const int pr = tid >> 4, pc = tid & 15;
            float acc = 0.0f;
            #pragma unroll
            for (int kh = 0; kh < RK; ++kh)
                #pragma unroll
                for (int kw = 0; kw < RK; ++kw)
                    acc += s_ssq[pr + kh][pc + kw];
            s_sq[tid] = acc * (1.0f / 75.0f);
        }
        __syncthreads();

        // issue next tile's staging into the other buffer (overlaps main phase)
        const int tn = s_next;
        if (tn < NT_TILES) stage_tile(mu_in, tn, s_row[cur ^ 1], tid);

        // decode current tile
        const int b  = t / 196;
        const int r2 = t - b * 196;
        int ho0 = (r2 / 14) * TS; if (ho0 > HOUT - TS) ho0 = HOUT - TS;
        int wo0 = (r2 % 14) * TS; if (wo0 > WOUT - TS) wo0 = WOUT - TS;

        // main: wave = 4 output rows x 16 px x 64 ch
        #pragma unroll 1
        for (int j = 0; j < 4; ++j) {
            const int rt = (wid << 2) | j;
            const size_t rowbase = (((size_t)b * HOUT + ho0 + rt) * WOUT + wo0) * KOUT;

            short8 pf[3];
            #pragma unroll
            for (int s = 0; s < 3; ++s) {
                int ridx = rt + 2 * s + (h2 >> 1);
                ridx = ridx > PATCH - 1 ? PATCH - 1 : ridx;   // k>=80 pad: value x 0-weight
                const float* rp = srow + ridx * 64 + 3 * p + 8 * (h2 & 1);
                union { unsigned u[4]; short8 v; } cv;
                asm("v_cvt_pk_bf16_f32 %0, %1, %2" : "=v"(cv.u[0]) : "v"(rp[0]), "v"(rp[1]));
                asm("v_cvt_pk_bf16_f32 %0, %1, %2" : "=v"(cv.u[1]) : "v"(rp[2]), "v"(rp[3]));
                asm("v_cvt_pk_bf16_f32 %0, %1, %2" : "=v"(cv.u[2]) : "v"(rp[4]), "v"(rp[5]));
                asm("v_cvt_pk_bf16_f32 %0, %1, %2" : "=v"(cv.u[3]) : "v"(rp[6]), "v"(rp[7]));
                pf[s] = cv.v;
            }

            v4f acc[4];
            #pragma unroll
            for (int nb = 0; nb < 4; ++nb) {
                v4f a = {0.0f, 0.0f, 0.0f, 0.0f};
                #pragma unroll
                for (int s = 0; s < 3; ++s)
                    a = __builtin_amdgcn_mfma_f32_16x16x32_bf16(wf[s * 4 + nb], pf[s], a, 0, 0, 0);
                acc[nb] = a;
            }

            // mu: D col = pixel p, rows = 4 ch at nb*16 + h2*4 (sector-complete)
            float* mp = out + rowbase + (size_t)p * KOUT + h2 * 4;
            #pragma unroll
            for (int nb = 0; nb < 4; ++nb)
                *(v4f*)(mp + nb * 16) = acc[nb];

            // sigma: kg-layout -> contiguous 1KB wave-stores
            float* sp = out + NTOT + rowbase + p * 4;
            #pragma unroll
            for (int pp = 0; pp < 4; ++pp) {
                const int px = (h2 << 2) | pp;
                const float sq = s_sq[(rt << 4) | px];
                v4f sg;
                sg.x = softplus_pos(wsg_kg.x * sq);
                sg.y = softplus_pos(wsg_kg.y * sq);
                sg.z = softplus_pos(wsg_kg.z * sq);
                sg.w = softplus_pos(wsg_kg.w * sq);
                *(v4f*)(sp + (size_t)px * KOUT) = sg;
            }
        }

        t = tn;
        cur ^= 1;
    }
}

extern "C" void kernel_launch(void* const* d_in, const int* in_sizes, int n_in,
                              void* d_out, int out_size, void* d_ws, size_t ws_size,
                              hipStream_t stream)
{
    (void)in_sizes; (void)n_in; (void)ws_size; (void)out_size;
    const float* mu_in   = (const float*)d_in[0];
    const float* w_mu    = (const float*)d_in[1];
    const float* w_sigma = (const float*)d_in[2];
    float* out = (float*)d_out;

    vdp_prep_kernel<<<1, 256, 0, stream>>>(w_mu, w_sigma, d_ws, out);
    vdp_conv_kernel<<<NBLK, 256, 0, stream>>>(mu_in, d_ws, out);
}